// Round 5
// baseline (237.762 us; speedup 1.0000x reference)
//
#include <hip/hip_runtime.h>
#include <stdint.h>

#define NHEADS 16
#define EDIM   1024
#define SEQ    2048
#define BATCH  4

typedef float  floatx4 __attribute__((ext_vector_type(4)));
typedef __bf16 bf16x8  __attribute__((ext_vector_type(8)));
typedef unsigned short u16;

__device__ __forceinline__ u16 f2bf(float f) {
  union { float f; unsigned int u; } v; v.f = f;
  return (u16)((v.u + 0x7fffu + ((v.u >> 16) & 1u)) >> 16);
}

// pack two floats -> (bf16(hi)<<16)|bf16(lo), round-half-up, 3 VALU ops
__device__ __forceinline__ unsigned int pkbf(float lo, float hi) {
  union { float f; unsigned int u; } a, c;
  a.f = lo; c.f = hi;
  return __builtin_amdgcn_perm(c.u + 0x8000u, a.u + 0x8000u, 0x07060302u);
}

__device__ __forceinline__ void gl2lds16(const u16* g, u16* l) {
  __builtin_amdgcn_global_load_lds(
      (const __attribute__((address_space(1))) unsigned int*)g,
      (__attribute__((address_space(3))) unsigned int*)l, 16, 0, 0);
}

// ---------------- fused fp32 -> bf16 conversion, 5 regions ----------------
__global__ void cvt_all(const float* __restrict__ x,  const float* __restrict__ wq,
                        const float* __restrict__ wk, const float* __restrict__ wv,
                        const float* __restrict__ wo, u16* __restrict__ xb,
                        u16* __restrict__ wqkv, u16* __restrict__ wob, float qscale) {
  const float* src; u16* dst; int n4; float sc = 1.f;
  switch (blockIdx.y) {
    case 0: src = x;  dst = xb;             n4 = 2097152; break;
    case 1: src = wq; dst = wqkv;           n4 = 262144; sc = qscale; break;
    case 2: src = wk; dst = wqkv + 1048576; n4 = 262144; break;
    case 3: src = wv; dst = wqkv + 2097152; n4 = 262144; break;
    default: src = wo; dst = wob;           n4 = 262144; break;
  }
  const int stride = gridDim.x * blockDim.x;
  for (int i = blockIdx.x * blockDim.x + threadIdx.x; i < n4; i += stride) {
    float4 f = ((const float4*)src)[i];
    uint2 o;
    o.x = pkbf(f.x * sc, f.y * sc);
    o.y = pkbf(f.z * sc, f.w * sc);
    ((uint2*)dst)[i] = o;
  }
}

// ---- Merged QKV projection GEMM, ring-3, 256 threads (4 waves 1Mx4N).
// A = Wqkv[3072][1024], B = Xb[8192][1024]. BM=128, BN=256, BK=32;
// 768 blocks (24 by x 32 bx), 2 blocks/CU (72 KiB LDS, 8 waves/CU).
// Wave-tile 128x64: af[8] + bfr[4] = 12 KB LDS-read per 32 MFMA
// (43.7 FLOP/LDS-byte, vs 32.8 at 64x64) - LDS-BW is the measured pole.
// Per K-tile: counted vmcnt(6) (tile t retired, t+1 in flight; never 0 in
// steady state) -> s_barrier -> stage tile t+2 (6 gl2lds/thread) into slot
// (t-1)%3 -> ds_read + MFMA burst. Chunk-XOR swizzle (chunk ^ (row>>1)&3,
// pre-swizzled global source, linear LDS dest) -> 0 conflicts measured.
// matid = rowA0>>10 block-uniform: 0/1 -> Q/K epilogue (packed uint2 along
// e); 2 -> swapped mfma + permuted V^T epilogue (R2/R4-proven).
__global__ __launch_bounds__(256, 2)
void gemm_qkv(const u16* __restrict__ A, const u16* __restrict__ B,
              u16* __restrict__ Cq, u16* __restrict__ Ck, u16* __restrict__ Cv) {
  constexpr int SLOT = (128 + 256) * 32;         // 12288 u16 per ring slot
  constexpr int BOFF = 128 * 32;                 // B region offset (u16)
  __shared__ __align__(16) u16 ring[3][SLOT];
  const int tid  = threadIdx.x;
  const int w    = tid >> 6, lane = tid & 63;    // w in 0..3
  const int quad = lane >> 4, l15 = lane & 15;
  const int bcol = w * 64;                       // wave-tile 128 x 64

  // XCD map: xcd = f&7 owns 4 consecutive B-panels (2 MB strip, L2-resident)
  const int f  = (int)blockIdx.x;
  const int g  = f >> 3;
  const int bx = (f & 7) * 4 + (g & 3);
  const int by = g >> 2;
  const int rowA0 = by * 128, rowB0 = bx * 256;
  const int matid = rowA0 >> 10;                 // 0=Q, 1=K, 2=V

  // staging: 16B/lane, 4 lanes per 64B row-chunk, pre-swizzled chunk.
  // A: wave w covers rows w*32..w*32+31 (2 loads); B: rows w*64..w*64+63 (4).
  const int cp = lane & 3;
  const int ra = w * 32 + (lane >> 2);
  const u16* srcA  = A + (size_t)(rowA0 + ra) * 1024 + (cp ^ ((ra >> 1) & 3)) * 8;
  const int rb = w * 64 + (lane >> 2);
  const u16* srcB  = B + (size_t)(rowB0 + rb) * 1024 + (cp ^ ((rb >> 1) & 3)) * 8;

#define STG(sl, tt)                                                          \
  {                                                                          \
    const int _ko = (tt) * 32;                                               \
    gl2lds16(srcA + _ko,             &ring[sl][0] + w * 1024);               \
    gl2lds16(srcA + 16 * 1024 + _ko, &ring[sl][0] + w * 1024 + 512);         \
    _Pragma("unroll")                                                        \
    for (int jj = 0; jj < 4; ++jj)                                           \
      gl2lds16(srcB + jj * 16 * 1024 + _ko,                                  \
               &ring[sl][BOFF] + w * 2048 + jj * 512);                       \
  }

  const floatx4 vzero = {0.f, 0.f, 0.f, 0.f};
  floatx4 acc[8][4];
#pragma unroll
  for (int mi = 0; mi < 8; ++mi)
#pragma unroll
    for (int ni = 0; ni < 4; ++ni) acc[mi][ni] = vzero;

  const int swz8 = (quad ^ ((l15 >> 1) & 3)) * 8;
  constexpr int NT = 32;                         // K / 32
  STG(0, 0);
  STG(1, 1);
  int cs = 0, ss = 2;

#define KLOOP(SWAPPED)                                                       \
  for (int t = 0; t < NT; ++t) {                                             \
    if (t < NT - 1) asm volatile("s_waitcnt vmcnt(6)" ::: "memory");         \
    else            asm volatile("s_waitcnt vmcnt(0)" ::: "memory");         \
    __builtin_amdgcn_s_barrier();                                            \
    if (t + 2 < NT) { STG(ss, t + 2); ss = (ss == 2) ? 0 : ss + 1; }         \
    const u16* As = &ring[cs][0];                                            \
    const u16* Bs = &ring[cs][BOFF];                                         \
    cs = (cs == 2) ? 0 : cs + 1;                                             \
    bf16x8 af[8], bfr[4];                                                    \
    _Pragma("unroll")                                                        \
    for (int j = 0; j < 8; ++j)                                              \
      af[j] = *(const bf16x8*)(As + (j * 16 + l15) * 32 + swz8);             \
    _Pragma("unroll")                                                        \
    for (int nj = 0; nj < 4; ++nj)                                           \
      bfr[nj] = *(const bf16x8*)(Bs + (bcol + nj * 16 + l15) * 32 + swz8);   \
    __builtin_amdgcn_s_setprio(1);                                           \
    _Pragma("unroll")                                                        \
    for (int mi = 0; mi < 8; ++mi)                                           \
      _Pragma("unroll")                                                      \
      for (int ni = 0; ni < 4; ++ni) {                                       \
        if (SWAPPED)                                                         \
          acc[mi][ni] = __builtin_amdgcn_mfma_f32_16x16x32_bf16(             \
              bfr[ni], af[mi], acc[mi][ni], 0, 0, 0);                        \
        else                                                                 \
          acc[mi][ni] = __builtin_amdgcn_mfma_f32_16x16x32_bf16(             \
              af[mi], bfr[ni], acc[mi][ni], 0, 0, 0);                        \
      }                                                                      \
    __builtin_amdgcn_s_setprio(0);                                           \
  }

  if (matid < 2) {
    KLOOP(0)
    u16* dst = (matid == 0) ? Cq : Ck;
#pragma unroll
    for (int mi = 0; mi < 8; ++mi)
#pragma unroll
      for (int ni = 0; ni < 4; ++ni) {
        const int e0 = rowA0 + mi * 16 + quad * 4;          // 4 consecutive e
        const int s  = rowB0 + bcol + ni * 16 + l15;
        const int e_loc = e0 & 1023;
        uint2 pk;
        pk.x = pkbf(acc[mi][ni][0], acc[mi][ni][1]);
        pk.y = pkbf(acc[mi][ni][2], acc[mi][ni][3]);
        *(uint2*)(dst + (size_t)s * 1024 + e_loc) = pk;
      }
  } else {
    KLOOP(1)
    // swapped orientation: rows = s (4 consecutive), col = e; permuted t-pos
#pragma unroll
    for (int mi = 0; mi < 8; ++mi)
#pragma unroll
      for (int ni = 0; ni < 4; ++ni) {
        const int e_loc = (rowA0 & 1023) + mi * 16 + l15;   // < 1024
        const int s_full = rowB0 + bcol + ni * 16 + quad * 4;
        const int pos = (s_full & ~31) | (quad << 3) | ((ni & 1) << 2);
        const int bb = pos >> 11, pos_loc = pos & 2047;
        uint2 pk;
        pk.x = pkbf(acc[mi][ni][0], acc[mi][ni][1]);
        pk.y = pkbf(acc[mi][ni][2], acc[mi][ni][3]);
        *(uint2*)(Cv + (size_t)(bb * 1024 + e_loc) * SEQ + pos_loc) = pk;
      }
  }
#undef KLOOP
#undef STG
}

// ---- out-projection GEMM, ring-3, 256 threads (4 waves 1Mx4N).
// A = Wob[1024][1024], B = Ctx[8192][1024]. BM=64, BN=256, BK=32;
// 512 blocks (16 by x 32 bx), 2 blocks/CU (60 KiB LDS). Wave-tile 64x64:
// 8 KB LDS-read per 16 MFMA = 32.8 FLOP/B (vs 21.8 at the old 64x32).
// Same ring-3 counted-vmcnt skeleton; 5 gl2lds/thread/tile -> vmcnt(5).
// fp32 float4 -> out[s][e].
__global__ __launch_bounds__(256, 2)
void gemm_out(const u16* __restrict__ A, const u16* __restrict__ B,
              float* __restrict__ C) {
  constexpr int SLOT = (64 + 256) * 32;          // 10240 u16 per ring slot
  constexpr int BOFF = 64 * 32;                  // 2048 u16
  __shared__ __align__(16) u16 ring[3][SLOT];
  const int tid  = threadIdx.x;
  const int w    = tid >> 6, lane = tid & 63;    // w in 0..3
  const int quad = lane >> 4, l15 = lane & 15;
  const int bcol = w * 64;

  const int f  = (int)blockIdx.x;
  const int g  = f >> 3;
  const int bx = (f & 7) * 4 + (g & 3);
  const int by = g >> 2;
  const int rowA0 = by * 64, rowB0 = bx * 256;

  const int cp = lane & 3;
  const int ra = w * 16 + (lane >> 2);           // A: wave w rows w*16..+15
  const u16* srcA = A + (size_t)(rowA0 + ra) * 1024 + (cp ^ ((ra >> 1) & 3)) * 8;
  const int rb = w * 64 + (lane >> 2);           // B: wave w rows w*64..+63
  const u16* srcB = B + (size_t)(rowB0 + rb) * 1024 + (cp ^ ((rb >> 1) & 3)) * 8;

#define STG(sl, tt)                                                          \
  {                                                                          \
    const int _ko = (tt) * 32;                                               \
    gl2lds16(srcA + _ko, &ring[sl][0] + w * 512);                            \
    _Pragma("unroll")                                                        \
    for (int jj = 0; jj < 4; ++jj)                                           \
      gl2lds16(srcB + jj * 16 * 1024 + _ko,                                  \
               &ring[sl][BOFF] + w * 2048 + jj * 512);                       \
  }

  const floatx4 vzero = {0.f, 0.f, 0.f, 0.f};
  floatx4 acc[4][4];
#pragma unroll
  for (int mi = 0; mi < 4; ++mi)
#pragma unroll
    for (int ni = 0; ni < 4; ++ni) acc[mi][ni] = vzero;

  const int swz8 = (quad ^ ((l15 >> 1) & 3)) * 8;
  constexpr int NT = 32;
  STG(0, 0);
  STG(1, 1);
  int cs = 0, ss = 2;

  for (int t = 0; t < NT; ++t) {
    if (t < NT - 1) asm volatile("s_waitcnt vmcnt(5)" ::: "memory");
    else            asm volatile("s_waitcnt vmcnt(0)" ::: "memory");
    __builtin_amdgcn_s_barrier();
    if (t + 2 < NT) { STG(ss, t + 2); ss = (ss == 2) ? 0 : ss + 1; }

    const u16* As = &ring[cs][0];
    const u16* Bs = &ring[cs][BOFF];
    cs = (cs == 2) ? 0 : cs + 1;
    bf16x8 af[4], bfr[4];
#pragma unroll
    for (int j = 0; j < 4; ++j)
      af[j] = *(const bf16x8*)(As + (j * 16 + l15) * 32 + swz8);
#pragma unroll
    for (int nj = 0; nj < 4; ++nj)
      bfr[nj] = *(const bf16x8*)(Bs + (bcol + nj * 16 + l15) * 32 + swz8);
    __builtin_amdgcn_s_setprio(1);
#pragma unroll
    for (int mi = 0; mi < 4; ++mi)
#pragma unroll
      for (int ni = 0; ni < 4; ++ni)
        acc[mi][ni] = __builtin_amdgcn_mfma_f32_16x16x32_bf16(af[mi], bfr[ni], acc[mi][ni], 0, 0, 0);
    __builtin_amdgcn_s_setprio(0);
  }
#undef STG

#pragma unroll
  for (int mi = 0; mi < 4; ++mi)
#pragma unroll
    for (int ni = 0; ni < 4; ++ni) {
      const int e0 = rowA0 + mi * 16 + quad * 4;
      const int s  = rowB0 + bcol + ni * 16 + l15;
      *(floatx4*)(C + (size_t)s * 1024 + e0) = acc[mi][ni];
    }
}

// ---------------- flash attention: waves split over (q-group, t-half) --------
// grid: x = bh (64), y -> qt = 15 - y (longest first). Block 512 = 8 waves:
// wave w = (qg = w>>1)*32 q-rows x (tg = w&1)*64 t-rows. Each wave reads only
// its t-half of K/V from LDS: 8 ak + 8 va b128 per 32 MFMAs. P in registers
// (C-layout -> PV B-operand; V pre-permuted in global so va are straight
// swizzled b128). Cross-t partial O and l reduced once through LDS at end.
__global__ __launch_bounds__(512, 4)
void attn_fwd(const u16* __restrict__ Q, const u16* __restrict__ K,
              const u16* __restrict__ Vp, u16* __restrict__ Ctx) {
  __shared__ u16 SMEM[4 * 8192];    // Ks[2] (2x16KB) then Vs[2] (2x16KB)
  const int tid  = threadIdx.x;
  const int w    = tid >> 6, lane = tid & 63;
  const int quad = lane >> 4, l15 = lane & 15;
  const int qg = w >> 1, tg = w & 1;
  const int bh = blockIdx.x, b = bh >> 4, h = bh & 15;
  const int qt = 15 - (int)blockIdx.y;   // longest blocks dispatched first
  const int kmax = qt;
  const int q0 = qt * 128 + qg * 32;

  // Q B-fragments (Q pre-scaled by 0.125*log2e via Wq cvt)
  bf16x8 bq[2][2];
#pragma unroll
  for (int ni = 0; ni < 2; ++ni)
#pragma unroll
    for (int ks = 0; ks < 2; ++ks) {
      const int qs = q0 + ni * 16 + l15;
      bq[ni][ks] = *(const bf16x8*)(Q + (size_t)(b * SEQ + qs) * EDIM + h * 64 + ks * 32 + quad * 8);
    }

  const floatx4 vzero = {0.f, 0.f, 0.f, 0.f};
  floatx4 o_acc[4][2];              // [d-tile][q-group], D[d][q] C-layout
  float l_acc[2] = {0.f, 0.f};      // per-lane partial row-sums
#pragma unroll
  for (int di = 0; di < 4; ++di)
#pragma unroll
    for (int ni = 0; ni < 2; ++ni) o_acc[di][ni] = vzero;

  const int krow = lane >> 3, kch = lane & 7;    // K staging: 8 rows x 8 chunks
  const int vrow = lane >> 4, vch = lane & 15;   // V staging: 4 rows x 16 chunks

#define STAGE_KV(buf, ktn)                                                          \
  {                                                                                 \
    _Pragma("unroll")                                                               \
    for (int ii = 0; ii < 2; ++ii) {                                                \
      const int r0 = w * 16 + ii * 8;                                               \
      const int row = r0 + krow;                                                    \
      gl2lds16(K + (size_t)(b * SEQ + (ktn) * 128 + row) * EDIM + h * 64 +          \
                   ((kch ^ (row & 7)) * 8),                                         \
               SMEM + (buf) * 8192 + r0 * 64);                                      \
      const int d0 = w * 8 + ii * 4;                                                \
      const int dd = d0 + vrow;                                                     \
      gl2lds16(Vp + (size_t)(bh * 64 + dd) * SEQ + (ktn) * 128 +                    \
                   ((vch ^ (dd & 15)) * 8),                                         \
               SMEM + 16384 + (buf) * 8192 + d0 * 128);                             \
    }                                                                               \
  }

  STAGE_KV(0, 0);

  for (int kt = 0; kt <= kmax; ++kt) {
    const int cur = kt & 1;
    __syncthreads();                // buf[cur] drained; buf[cur^1] readers done
    if (kt < kmax) STAGE_KV(cur ^ 1, kt + 1);
    const u16* Ksc = SMEM + cur * 8192;
    const u16* Vsc = SMEM + 16384 + cur * 8192;

    // ---- QK + fused softmax, per mi (keeps s_acc live-range at 8 regs) ----
    unsigned int pk[2][2][4];       // [ni][ks][dword] PV B-operand
#pragma unroll
    for (int mi = 0; mi < 4; ++mi) {
      floatx4 s[2] = {vzero, vzero};
#pragma unroll
      for (int ks = 0; ks < 2; ++ks) {
        bf16x8 ak = *(const bf16x8*)(Ksc + (tg * 64 + mi * 16 + l15) * 64 +
                                     (((ks * 4 + quad) ^ (l15 & 7)) * 8));
#pragma unroll
        for (int ni = 0; ni < 2; ++ni)
          s[ni] = __builtin_amdgcn_mfma_f32_16x16x32_bf16(ak, bq[ni][ks], s[ni], 0, 0, 0);
      }
      if (kt == kmax) {             // causal mask, diagonal tile only
#pragma unroll
        for (int ni = 0; ni < 2; ++ni)
#pragma unroll
          for (int r = 0; r < 4; ++r) {
            const int t_loc = tg * 64 + mi * 16 + quad * 4 + r;
            const int q_loc = qg * 32 + ni * 16 + l15;
            if (t_loc > q_loc) s[ni][r] = -1e30f;
          }
      }
#pragma unroll
      for (int ni = 0; ni < 2; ++ni) {
        float p0 = __builtin_amdgcn_exp2f(s[ni][0]);
        float p1 = __builtin_amdgcn_exp2f(s[ni][1]);
        float p2 = __builtin_amdgcn_exp2f(s[ni][2]);
        float p3 = __builtin_amdgcn_exp2f(s[ni][3]);
        l_acc[ni] += (p0 + p1) + (p2 + p3);
        pk[ni][mi >> 1][(mi & 1) * 2 + 0] = pkbf(p0, p1);
        pk[ni][mi >> 1][(mi & 1) * 2 + 1] = pkbf(p2, p3);
      }
    }

    // ---- PV on the wave's t-half (permuted layout -> swizzled b128) ----
#pragma unroll
    for (int ks = 0; ks < 2; ++ks) {
      bf16x8 va[4];
#pragma unroll
      for (int di = 0; di < 4; ++di)
        va[di] = *(const bf16x8*)(Vsc + (di * 16 + l15) * 128 +
                                  (((tg * 8 + ks * 4 + quad) ^ l15) * 8));
#pragma unroll
      for (int ni = 0; ni < 2; ++ni) {
        union { unsigned int u[4]; bf16x8 v; } pb;
        pb.u[0] = pk[ni][ks][0]; pb.u[1] = pk[ni][ks][1];
        pb.u[2] = pk[ni][ks][2]; pb.u[3] = pk[ni][ks][3];
#pragma unroll
        for (int di = 0; di < 4; ++di)
          o_acc[di][ni] = __builtin_amdgcn_mfma_f32_16x16x32_bf16(va[di], pb.v, o_acc[di][ni], 0, 0, 0);
      }
    }
  }

  // ---- epilogue: reduce tg partials through LDS, divide by l, store ----
  float lt[2];
#pragma unroll
  for (int ni = 0; ni < 2; ++ni) {
    float v = l_acc[ni];
    v += __shfl_xor(v, 16, 64);
    v += __shfl_xor(v, 32, 64);
    lt[ni] = v;
  }
  __syncthreads();                  // everyone done with K/V LDS
  float* red  = (float*)SMEM;       // O partials: [qg][d][q] stride 33 (8448 f)
  float* lred = red + 8448;         // l partials: [qg*32 + q] (128 f)
  if (tg == 1) {
#pragma unroll
    for (int ni = 0; ni < 2; ++ni) {
#pragma unroll
      for (int di = 0; di < 4; ++di)
#pragma unroll
        for (int r = 0; r < 4; ++r)
          red[qg * 2112 + (di * 16 + quad * 4 + r) * 33 + ni * 16 + l15] = o_acc[di][ni][r];
      if (quad == 0) lred[qg * 32 + ni * 16 + l15] = lt[ni];
    }
  }
  __syncthreads();
  if (tg == 0) {
#pragma unroll
    for (int ni = 0; ni < 2; ++ni) {
      const float rl = 1.f / (lt[ni] + lred[qg * 32 + ni * 16 + l15]);
      const int qs = q0 + ni * 16 + l15;
#pragma unroll
      for (int di = 0; di < 4; ++di) {
        float v0 = (o_acc[di][ni][0] + red[qg * 2112 + (di * 16 + quad * 4 + 0) * 33 + ni * 16 + l15]) * rl;
        float v1 = (o_acc[di][ni][1] + red[qg * 2112 + (di * 16 + quad * 4 + 1) * 33 + ni * 16 + l15]) * rl;
        float v2 = (o_acc[di][ni][2] + red[qg * 2112 + (di * 16 + quad * 4 + 2) * 33 + ni * 16 + l15]) * rl;
        float v3 = (o_acc[di][ni][3] + red[qg * 2112 + (di * 16 + quad * 4 + 3) * 33 + ni * 16 + l15]) * rl;
        uint2 ov;
        ov.x = pkbf(v0, v1);
        ov.y = pkbf(v2, v3);
        *(uint2*)(Ctx + (size_t)(b * SEQ + qs) * EDIM + h * 64 + di * 16 + quad * 4) = ov;
      }
    }
  }
#undef STAGE_KV
}

// ---------------- launch ----------------
extern "C" void kernel_launch(void* const* d_in, const int* in_sizes, int n_in,
                              void* d_out, int out_size, void* d_ws, size_t ws_size,
                              hipStream_t stream) {
  const float* x  = (const float*)d_in[0];
  const float* Wq = (const float*)d_in[1];
  const float* Wk = (const float*)d_in[2];
  const float* Wv = (const float*)d_in[3];
  const float* Wo = (const float*)d_in[4];
  float* out = (float*)d_out;
  u16* ws = (u16*)d_ws;

  const size_t ME = (size_t)BATCH * SEQ * EDIM;  // 8388608
  u16* Xb   = ws;                                // [8192][1024] bf16
  u16* Wqkv = Xb + ME;                           // [3072][1024]
  u16* Wob  = Wqkv + 3u * 1024 * 1024;           // [1024][1024]
  u16* Qb   = Wob + 1024u * 1024;                // [B,S,E] (pre-scaled)
  u16* Kb   = Qb + ME;
  u16* Vpb  = Kb + ME;                           // V^T permuted: [b*1024+hd][2048]
  u16* Ctx  = Vpb + ME;                          // ends at ~88 MB

  const float qscale = 0.125f * 1.44269504f;     // 1/sqrt(64) * log2(e)

  cvt_all<<<dim3(512, 5), 256, 0, stream>>>(x, Wq, Wk, Wv, Wo, Xb, Wqkv, Wob, qscale);
  // merged QKV: M=3072 (24 by) x N=8192 (32 bx), BN=256 -> 768 blocks
  gemm_qkv<<<dim3(768), 256, 0, stream>>>(Wqkv, Xb, Qb, Kb, Vpb);
  attn_fwd<<<dim3(64, 16), 512, 0, stream>>>(Qb, Kb, Vpb, Ctx);
  // out-proj: M=1024 (16 by) x N=8192 (32 bx), BM=64/BN=256 -> 512 blocks
  gemm_out<<<dim3(512), 256, 0, stream>>>(Wob, Ctx, out);
}

// Round 6
// 215.009 us; speedup vs baseline: 1.1058x; 1.1058x over previous
//
#include <hip/hip_runtime.h>
#include <stdint.h>

#define NHEADS 16
#define EDIM   1024
#define SEQ    2048
#define BATCH  4

typedef float  floatx4 __attribute__((ext_vector_type(4)));
typedef __bf16 bf16x8  __attribute__((ext_vector_type(8)));
typedef unsigned short u16;

__device__ __forceinline__ u16 f2bf(float f) {
  union { float f; unsigned int u; } v; v.f = f;
  return (u16)((v.u + 0x7fffu + ((v.u >> 16) & 1u)) >> 16);
}

// pack two floats -> (bf16(hi)<<16)|bf16(lo), round-half-up, 3 VALU ops
__device__ __forceinline__ unsigned int pkbf(float lo, float hi) {
  union { float f; unsigned int u; } a, c;
  a.f = lo; c.f = hi;
  return __builtin_amdgcn_perm(c.u + 0x8000u, a.u + 0x8000u, 0x07060302u);
}

// single-instruction HW pack (RNE): D[15:0]=bf16(lo), D[31:16]=bf16(hi)
__device__ __forceinline__ unsigned int cvtpk(float lo, float hi) {
  unsigned int r;
  asm("v_cvt_pk_bf16_f32 %0, %1, %2" : "=v"(r) : "v"(lo), "v"(hi));
  return r;
}

__device__ __forceinline__ void gl2lds16(const u16* g, u16* l) {
  __builtin_amdgcn_global_load_lds(
      (const __attribute__((address_space(1))) unsigned int*)g,
      (__attribute__((address_space(3))) unsigned int*)l, 16, 0, 0);
}

// ---------------- fused fp32 -> bf16 conversion, 5 regions ----------------
__global__ void cvt_all(const float* __restrict__ x,  const float* __restrict__ wq,
                        const float* __restrict__ wk, const float* __restrict__ wv,
                        const float* __restrict__ wo, u16* __restrict__ xb,
                        u16* __restrict__ wqkv, u16* __restrict__ wob, float qscale) {
  const float* src; u16* dst; int n4; float sc = 1.f;
  switch (blockIdx.y) {
    case 0: src = x;  dst = xb;             n4 = 2097152; break;
    case 1: src = wq; dst = wqkv;           n4 = 262144; sc = qscale; break;
    case 2: src = wk; dst = wqkv + 1048576; n4 = 262144; break;
    case 3: src = wv; dst = wqkv + 2097152; n4 = 262144; break;
    default: src = wo; dst = wob;           n4 = 262144; break;
  }
  const int stride = gridDim.x * blockDim.x;
  for (int i = blockIdx.x * blockDim.x + threadIdx.x; i < n4; i += stride) {
    float4 f = ((const float4*)src)[i];
    uint2 o;
    o.x = pkbf(f.x * sc, f.y * sc);
    o.y = pkbf(f.z * sc, f.w * sc);
    ((uint2*)dst)[i] = o;
  }
}

// ---- Merged QKV projection GEMM, ring-3 structure (R4-proven, 812 TF).
// A = Wqkv[3072][1024], B = Xb[8192][1024]. BM=128, BN=256, BK=32;
// 768 blocks (24 by x 32 bx), 512 thr (8 waves 2Mx4N, wave-tile 64x64),
// 2 blocks/CU (72 KiB LDS) = 16 waves/CU. matid = rowA0>>10 block-uniform:
//   0/1 (Wq/Wk): mfma(af,bfr) -> D[e][s]; packed uint2 along e into Qb/Kb.
//   2   (Wv):    swapped mfma(bfr,af) -> D[s][e]; V^T stored with PERMUTED
//                t-order (pos=(s&~31)|(quad<<3)|((ni&1)<<2)) for attn PV.
// Per K-tile: counted vmcnt(3) (tile t retired, t+1 in flight; never 0 in
// steady state) -> s_barrier -> stage tile t+2 into slot (t-1)%3 -> ds_read +
// MFMA. Chunk-XOR swizzle (chunk ^ (row>>1)&3; pre-swizzled global source,
// linear LDS dest) -> 0 conflicts measured.
__global__ __launch_bounds__(512, 4)
void gemm_qkv(const u16* __restrict__ A, const u16* __restrict__ B,
              u16* __restrict__ Cq, u16* __restrict__ Ck, u16* __restrict__ Cv) {
  constexpr int SLOT = (128 + 256) * 32;         // u16 per ring slot
  constexpr int BOFF = 128 * 32;                 // B region offset in slot
  __shared__ __align__(16) u16 ring[3][SLOT];
  const int tid  = threadIdx.x;
  const int w    = tid >> 6, lane = tid & 63;
  const int quad = lane >> 4, l15 = lane & 15;
  const int wrow = (w >> 2) * 64, bcol = (w & 3) * 64;

  // XCD map: xcd = f&7 owns 4 consecutive B-panels (2 MB strip, L2-resident)
  const int f  = (int)blockIdx.x;
  const int g  = f >> 3;
  const int bx = (f & 7) * 4 + (g & 3);
  const int by = g >> 2;
  const int rowA0 = by * 128, rowB0 = bx * 256;
  const int matid = rowA0 >> 10;                 // 0=Q, 1=K, 2=V

  // staging sources: 16B/lane, 4 lanes per 64B row-chunk, pre-swizzled chunk
  const int cp = lane & 3;
  const int ra = w * 16 + (lane >> 2);
  const u16* srcA  = A + (size_t)(rowA0 + ra) * 1024 + (cp ^ ((ra >> 1) & 3)) * 8;
  const int rb0 = w * 32 + (lane >> 2);
  const u16* srcB0 = B + (size_t)(rowB0 + rb0) * 1024 + (cp ^ ((rb0 >> 1) & 3)) * 8;
  const u16* srcB1 = srcB0 + 16 * 1024;   // row+16: same swizzle key

#define STG(sl, tt)                                                          \
  {                                                                          \
    const int _ko = (tt) * 32;                                               \
    gl2lds16(srcA + _ko, &ring[sl][0] + w * 512);                            \
    gl2lds16(srcB0 + _ko, &ring[sl][BOFF] + w * 1024);                       \
    gl2lds16(srcB1 + _ko, &ring[sl][BOFF] + w * 1024 + 512);                 \
  }

  const floatx4 vzero = {0.f, 0.f, 0.f, 0.f};
  floatx4 acc[4][4];
#pragma unroll
  for (int mi = 0; mi < 4; ++mi)
#pragma unroll
    for (int ni = 0; ni < 4; ++ni) acc[mi][ni] = vzero;

  const int swz8 = (quad ^ ((l15 >> 1) & 3)) * 8;
  constexpr int NT = 32;                         // K / 32
  STG(0, 0);
  STG(1, 1);
  int cs = 0, ss = 2;

#define KLOOP(SWAPPED)                                                       \
  for (int t = 0; t < NT; ++t) {                                             \
    if (t < NT - 1) asm volatile("s_waitcnt vmcnt(3)" ::: "memory");         \
    else            asm volatile("s_waitcnt vmcnt(0)" ::: "memory");         \
    __builtin_amdgcn_s_barrier();                                            \
    if (t + 2 < NT) { STG(ss, t + 2); ss = (ss == 2) ? 0 : ss + 1; }         \
    const u16* As = &ring[cs][0];                                            \
    const u16* Bs = &ring[cs][BOFF];                                         \
    cs = (cs == 2) ? 0 : cs + 1;                                             \
    bf16x8 af[4], bfr[4];                                                    \
    _Pragma("unroll")                                                        \
    for (int j = 0; j < 4; ++j)                                              \
      af[j] = *(const bf16x8*)(As + (wrow + j * 16 + l15) * 32 + swz8);      \
    _Pragma("unroll")                                                        \
    for (int nj = 0; nj < 4; ++nj)                                           \
      bfr[nj] = *(const bf16x8*)(Bs + (bcol + nj * 16 + l15) * 32 + swz8);   \
    __builtin_amdgcn_s_setprio(1);                                           \
    _Pragma("unroll")                                                        \
    for (int mi = 0; mi < 4; ++mi)                                           \
      _Pragma("unroll")                                                      \
      for (int ni = 0; ni < 4; ++ni) {                                       \
        if (SWAPPED)                                                         \
          acc[mi][ni] = __builtin_amdgcn_mfma_f32_16x16x32_bf16(             \
              bfr[ni], af[mi], acc[mi][ni], 0, 0, 0);                        \
        else                                                                 \
          acc[mi][ni] = __builtin_amdgcn_mfma_f32_16x16x32_bf16(             \
              af[mi], bfr[ni], acc[mi][ni], 0, 0, 0);                        \
      }                                                                      \
    __builtin_amdgcn_s_setprio(0);                                           \
  }

  if (matid < 2) {
    KLOOP(0)
    u16* dst = (matid == 0) ? Cq : Ck;
#pragma unroll
    for (int mi = 0; mi < 4; ++mi)
#pragma unroll
      for (int ni = 0; ni < 4; ++ni) {
        const int e0 = rowA0 + wrow + mi * 16 + quad * 4;   // 4 consecutive e
        const int s  = rowB0 + bcol + ni * 16 + l15;
        const int e_loc = e0 & 1023;
        uint2 pk;
        pk.x = pkbf(acc[mi][ni][0], acc[mi][ni][1]);
        pk.y = pkbf(acc[mi][ni][2], acc[mi][ni][3]);
        *(uint2*)(dst + (size_t)s * 1024 + e_loc) = pk;
      }
  } else {
    KLOOP(1)
    // swapped orientation: rows = s (4 consecutive), col = e; permuted t-pos
#pragma unroll
    for (int mi = 0; mi < 4; ++mi)
#pragma unroll
      for (int ni = 0; ni < 4; ++ni) {
        const int e_loc = (rowA0 & 1023) + wrow + mi * 16 + l15;   // < 1024
        const int s_full = rowB0 + bcol + ni * 16 + quad * 4;
        const int pos = (s_full & ~31) | (quad << 3) | ((ni & 1) << 2);
        const int bb = pos >> 11, pos_loc = pos & 2047;
        uint2 pk;
        pk.x = pkbf(acc[mi][ni][0], acc[mi][ni][1]);
        pk.y = pkbf(acc[mi][ni][2], acc[mi][ni][3]);
        *(uint2*)(Cv + (size_t)(bb * 1024 + e_loc) * SEQ + pos_loc) = pk;
      }
  }
#undef KLOOP
#undef STG
}

// ---- out-projection GEMM, ring-3 (R4-proven). A=Wob[1024][1024],
// B=Ctx[8192][1024]. BM=128, BN=128, BK=32; 512 blocks, 512 thr, 2/CU.
// fp32 float4 -> out[s][e].
__global__ __launch_bounds__(512, 4)
void gemm_out(const u16* __restrict__ A, const u16* __restrict__ B,
              float* __restrict__ C) {
  constexpr int SLOT = 256 * 32;
  constexpr int BOFF = 128 * 32;
  __shared__ __align__(16) u16 ring[3][SLOT];
  const int tid  = threadIdx.x;
  const int w    = tid >> 6, lane = tid & 63;
  const int quad = lane >> 4, l15 = lane & 15;
  const int wrow = (w >> 2) * 64, bcol = (w & 3) * 32;

  const int f  = (int)blockIdx.x;
  const int g  = f >> 3;
  const int bx = (f & 7) * 8 + (g & 7);
  const int by = g >> 3;
  const int rowA0 = by * 128, rowB0 = bx * 128;

  const int cp = lane & 3;
  const int ra = w * 16 + (lane >> 2);
  const u16* srcA  = A + (size_t)(rowA0 + ra) * 1024 + (cp ^ ((ra >> 1) & 3)) * 8;
  const u16* srcB0 = B + (size_t)(rowB0 + ra) * 1024 + (cp ^ ((ra >> 1) & 3)) * 8;

#define STG(sl, tt)                                                          \
  {                                                                          \
    const int _ko = (tt) * 32;                                               \
    gl2lds16(srcA + _ko, &ring[sl][0] + w * 512);                            \
    gl2lds16(srcB0 + _ko, &ring[sl][BOFF] + w * 512);                        \
  }

  const floatx4 vzero = {0.f, 0.f, 0.f, 0.f};
  floatx4 acc[4][2];
#pragma unroll
  for (int mi = 0; mi < 4; ++mi)
#pragma unroll
    for (int ni = 0; ni < 2; ++ni) acc[mi][ni] = vzero;

  const int swz8 = (quad ^ ((l15 >> 1) & 3)) * 8;
  constexpr int NT = 32;
  STG(0, 0);
  STG(1, 1);
  int cs = 0, ss = 2;

  for (int t = 0; t < NT; ++t) {
    if (t < NT - 1) asm volatile("s_waitcnt vmcnt(2)" ::: "memory");
    else            asm volatile("s_waitcnt vmcnt(0)" ::: "memory");
    __builtin_amdgcn_s_barrier();
    if (t + 2 < NT) { STG(ss, t + 2); ss = (ss == 2) ? 0 : ss + 1; }

    const u16* As = &ring[cs][0];
    const u16* Bs = &ring[cs][BOFF];
    cs = (cs == 2) ? 0 : cs + 1;
    bf16x8 af[4], bfr[2];
#pragma unroll
    for (int j = 0; j < 4; ++j)
      af[j] = *(const bf16x8*)(As + (wrow + j * 16 + l15) * 32 + swz8);
#pragma unroll
    for (int nj = 0; nj < 2; ++nj)
      bfr[nj] = *(const bf16x8*)(Bs + (bcol + nj * 16 + l15) * 32 + swz8);
    __builtin_amdgcn_s_setprio(1);
#pragma unroll
    for (int mi = 0; mi < 4; ++mi)
#pragma unroll
      for (int ni = 0; ni < 2; ++ni)
        acc[mi][ni] = __builtin_amdgcn_mfma_f32_16x16x32_bf16(af[mi], bfr[ni], acc[mi][ni], 0, 0, 0);
    __builtin_amdgcn_s_setprio(0);
  }
#undef STG

#pragma unroll
  for (int mi = 0; mi < 4; ++mi)
#pragma unroll
    for (int ni = 0; ni < 2; ++ni) {
      const int e0 = rowA0 + wrow + mi * 16 + quad * 4;
      const int s  = rowB0 + bcol + ni * 16 + l15;
      *(floatx4*)(C + (size_t)s * 1024 + e0) = acc[mi][ni];
    }
}

// ---------------- flash attention: waves split over (q-group, t-half) --------
// grid: x = bh (64), y -> qt = 15 - y (longest first). Block 512 = 8 waves:
// wave w = (qg = w>>1)*32 q-rows x (tg = w&1)*64 t-rows. VALU-diet version:
// P-pack via v_cvt_pk_bf16_f32 (1 op vs 3), row-sum l via MFMA with a ones
// A-operand (moves 24 adds/kt off the saturated VALU pipe; D[r][q] is
// row-uniform so the epilogue shuffle-reduce is deleted too).
__global__ __launch_bounds__(512, 4)
void attn_fwd(const u16* __restrict__ Q, const u16* __restrict__ K,
              const u16* __restrict__ Vp, u16* __restrict__ Ctx) {
  __shared__ u16 SMEM[4 * 8192];    // Ks[2] (2x16KB) then Vs[2] (2x16KB)
  const int tid  = threadIdx.x;
  const int w    = tid >> 6, lane = tid & 63;
  const int quad = lane >> 4, l15 = lane & 15;
  const int qg = w >> 1, tg = w & 1;
  const int bh = blockIdx.x, b = bh >> 4, h = bh & 15;
  const int qt = 15 - (int)blockIdx.y;   // longest blocks dispatched first
  const int kmax = qt;
  const int q0 = qt * 128 + qg * 32;

  // Q B-fragments (Q pre-scaled by 0.125*log2e via Wq cvt)
  bf16x8 bq[2][2];
#pragma unroll
  for (int ni = 0; ni < 2; ++ni)
#pragma unroll
    for (int ks = 0; ks < 2; ++ks) {
      const int qs = q0 + ni * 16 + l15;
      bq[ni][ks] = *(const bf16x8*)(Q + (size_t)(b * SEQ + qs) * EDIM + h * 64 + ks * 32 + quad * 8);
    }

  union { unsigned int u[4]; bf16x8 v; } ones;   // bf16 1.0 x8
  ones.u[0] = ones.u[1] = ones.u[2] = ones.u[3] = 0x3F803F80u;

  const floatx4 vzero = {0.f, 0.f, 0.f, 0.f};
  floatx4 o_acc[4][2];              // [d-tile][q-group], D[d][q] C-layout
  floatx4 l_vacc[2] = {vzero, vzero};   // MFMA row-sum acc (row-uniform)
#pragma unroll
  for (int di = 0; di < 4; ++di)
#pragma unroll
    for (int ni = 0; ni < 2; ++ni) o_acc[di][ni] = vzero;

  const int krow = lane >> 3, kch = lane & 7;    // K staging: 8 rows x 8 chunks
  const int vrow = lane >> 4, vch = lane & 15;   // V staging: 4 rows x 16 chunks

#define STAGE_KV(buf, ktn)                                                          \
  {                                                                                 \
    _Pragma("unroll")                                                               \
    for (int ii = 0; ii < 2; ++ii) {                                                \
      const int r0 = w * 16 + ii * 8;                                               \
      const int row = r0 + krow;                                                    \
      gl2lds16(K + (size_t)(b * SEQ + (ktn) * 128 + row) * EDIM + h * 64 +          \
                   ((kch ^ (row & 7)) * 8),                                         \
               SMEM + (buf) * 8192 + r0 * 64);                                      \
      const int d0 = w * 8 + ii * 4;                                                \
      const int dd = d0 + vrow;                                                     \
      gl2lds16(Vp + (size_t)(bh * 64 + dd) * SEQ + (ktn) * 128 +                    \
                   ((vch ^ (dd & 15)) * 8),                                         \
               SMEM + 16384 + (buf) * 8192 + d0 * 128);                             \
    }                                                                               \
  }

  STAGE_KV(0, 0);

  for (int kt = 0; kt <= kmax; ++kt) {
    const int cur = kt & 1;
    __syncthreads();                // buf[cur] drained; buf[cur^1] readers done
    if (kt < kmax) STAGE_KV(cur ^ 1, kt + 1);
    const u16* Ksc = SMEM + cur * 8192;
    const u16* Vsc = SMEM + 16384 + cur * 8192;

    // ---- QK + fused softmax, per mi (keeps s_acc live-range at 8 regs) ----
    unsigned int pk[2][2][4];       // [ni][ks][dword] PV B-operand
#pragma unroll
    for (int mi = 0; mi < 4; ++mi) {
      floatx4 s[2] = {vzero, vzero};
#pragma unroll
      for (int ks = 0; ks < 2; ++ks) {
        bf16x8 ak = *(const bf16x8*)(Ksc + (tg * 64 + mi * 16 + l15) * 64 +
                                     (((ks * 4 + quad) ^ (l15 & 7)) * 8));
#pragma unroll
        for (int ni = 0; ni < 2; ++ni)
          s[ni] = __builtin_amdgcn_mfma_f32_16x16x32_bf16(ak, bq[ni][ks], s[ni], 0, 0, 0);
      }
      if (kt == kmax) {             // causal mask, diagonal tile only
#pragma unroll
        for (int ni = 0; ni < 2; ++ni)
#pragma unroll
          for (int r = 0; r < 4; ++r) {
            const int t_loc = tg * 64 + mi * 16 + quad * 4 + r;
            const int q_loc = qg * 32 + ni * 16 + l15;
            if (t_loc > q_loc) s[ni][r] = -1e30f;
          }
      }
#pragma unroll
      for (int ni = 0; ni < 2; ++ni) {
        float p0 = __builtin_amdgcn_exp2f(s[ni][0]);
        float p1 = __builtin_amdgcn_exp2f(s[ni][1]);
        float p2 = __builtin_amdgcn_exp2f(s[ni][2]);
        float p3 = __builtin_amdgcn_exp2f(s[ni][3]);
        pk[ni][mi >> 1][(mi & 1) * 2 + 0] = cvtpk(p0, p1);
        pk[ni][mi >> 1][(mi & 1) * 2 + 1] = cvtpk(p2, p3);
      }
    }

    // ---- PV + l-sum on the wave's t-half ----
#pragma unroll
    for (int ks = 0; ks < 2; ++ks) {
      bf16x8 va[4];
#pragma unroll
      for (int di = 0; di < 4; ++di)
        va[di] = *(const bf16x8*)(Vsc + (di * 16 + l15) * 128 +
                                  (((tg * 8 + ks * 4 + quad) ^ l15) * 8));
#pragma unroll
      for (int ni = 0; ni < 2; ++ni) {
        union { unsigned int u[4]; bf16x8 v; } pb;
        pb.u[0] = pk[ni][ks][0]; pb.u[1] = pk[ni][ks][1];
        pb.u[2] = pk[ni][ks][2]; pb.u[3] = pk[ni][ks][3];
        l_vacc[ni] = __builtin_amdgcn_mfma_f32_16x16x32_bf16(ones.v, pb.v, l_vacc[ni], 0, 0, 0);
#pragma unroll
        for (int di = 0; di < 4; ++di)
          o_acc[di][ni] = __builtin_amdgcn_mfma_f32_16x16x32_bf16(va[di], pb.v, o_acc[di][ni], 0, 0, 0);
      }
    }
  }

  // ---- epilogue: reduce tg partials through LDS, divide by l, store ----
  // l_vacc[ni] rows are uniform (ones A-operand): lt = element 0 directly.
  float lt[2];
#pragma unroll
  for (int ni = 0; ni < 2; ++ni) lt[ni] = l_vacc[ni][0];
  __syncthreads();                  // everyone done with K/V LDS
  float* red  = (float*)SMEM;       // O partials: [qg][d][q] stride 33 (8448 f)
  float* lred = red + 8448;         // l partials: [qg*32 + q] (128 f)
  if (tg == 1) {
#pragma unroll
    for (int ni = 0; ni < 2; ++ni) {
#pragma unroll
      for (int di = 0; di < 4; ++di)
#pragma unroll
        for (int r = 0; r < 4; ++r)
          red[qg * 2112 + (di * 16 + quad * 4 + r) * 33 + ni * 16 + l15] = o_acc[di][ni][r];
      if (quad == 0) lred[qg * 32 + ni * 16 + l15] = lt[ni];
    }
  }
  __syncthreads();
  if (tg == 0) {
#pragma unroll
    for (int ni = 0; ni < 2; ++ni) {
      const float rl = 1.f / (lt[ni] + lred[qg * 32 + ni * 16 + l15]);
      const int qs = q0 + ni * 16 + l15;
#pragma unroll
      for (int di = 0; di < 4; ++di) {
        float v0 = (o_acc[di][ni][0] + red[qg * 2112 + (di * 16 + quad * 4 + 0) * 33 + ni * 16 + l15]) * rl;
        float v1 = (o_acc[di][ni][1] + red[qg * 2112 + (di * 16 + quad * 4 + 1) * 33 + ni * 16 + l15]) * rl;
        float v2 = (o_acc[di][ni][2] + red[qg * 2112 + (di * 16 + quad * 4 + 2) * 33 + ni * 16 + l15]) * rl;
        float v3 = (o_acc[di][ni][3] + red[qg * 2112 + (di * 16 + quad * 4 + 3) * 33 + ni * 16 + l15]) * rl;
        uint2 ov;
        ov.x = cvtpk(v0, v1);
        ov.y = cvtpk(v2, v3);
        *(uint2*)(Ctx + (size_t)(b * SEQ + qs) * EDIM + h * 64 + di * 16 + quad * 4) = ov;
      }
    }
  }
#undef STAGE_KV
}

// ---------------- launch ----------------
extern "C" void kernel_launch(void* const* d_in, const int* in_sizes, int n_in,
                              void* d_out, int out_size, void* d_ws, size_t ws_size,
                              hipStream_t stream) {
  const float* x  = (const float*)d_in[0];
  const float* Wq = (const float*)d_in[1];
  const float* Wk = (const float*)d_in[2];
  const float* Wv = (const float*)d_in[3];
  const float* Wo = (const float*)d_in[4];
  float* out = (float*)d_out;
  u16* ws = (u16*)d_ws;

  const size_t ME = (size_t)BATCH * SEQ * EDIM;  // 8388608
  u16* Xb   = ws;                                // [8192][1024] bf16
  u16* Wqkv = Xb + ME;                           // [3072][1024]
  u16* Wob  = Wqkv + 3u * 1024 * 1024;           // [1024][1024]
  u16* Qb   = Wob + 1024u * 1024;                // [B,S,E] (pre-scaled)
  u16* Kb   = Qb + ME;
  u16* Vpb  = Kb + ME;                           // V^T permuted: [b*1024+hd][2048]
  u16* Ctx  = Vpb + ME;                          // ends at ~88 MB

  const float qscale = 0.125f * 1.44269504f;     // 1/sqrt(64) * log2(e)

  cvt_all<<<dim3(512, 5), 256, 0, stream>>>(x, Wq, Wk, Wv, Wo, Xb, Wqkv, Wob, qscale);
  // merged QKV: M=3072 (24 by) x N=8192 (32 bx), BN=256 -> 768 blocks
  gemm_qkv<<<dim3(768), 512, 0, stream>>>(Wqkv, Xb, Qb, Kb, Vpb);
  attn_fwd<<<dim3(64, 16), 512, 0, stream>>>(Qb, Kb, Vpb, Ctx);
  // out-proj: M=1024 (8 by) x N=8192 (64 bx), BN=128 -> 512 blocks
  gemm_out<<<dim3(512), 512, 0, stream>>>(Wob, Ctx, out);
}